// Round 6
// baseline (386.919 us; speedup 1.0000x reference)
//
#include <hip/hip_runtime.h>
#include <hip/hip_bf16.h>
#include <hip/hip_fp16.h>
#include <math.h>

#define T_TOK 2048
#define HDIM  1024
#define NEXP  16
#define IDIM  768
#define BM    128
#define BK    64
#define LDA   72      // LDS row stride in halfs: 144 B -> 2-way bank aliasing (free)
#define MAXROWS 6144  // 4096 real slots + 16*127 max pad, rounded to 128

using f16   = _Float16;
using f16x4 = __attribute__((ext_vector_type(4))) _Float16;
using f16x8 = __attribute__((ext_vector_type(8))) _Float16;
using f32x4 = __attribute__((ext_vector_type(4))) float;

__device__ __forceinline__ f16x8 cvt2(float4 a, float4 b) {
    f16x8 r;
    r[0] = (f16)a.x; r[1] = (f16)a.y; r[2] = (f16)a.z; r[3] = (f16)a.w;
    r[4] = (f16)b.x; r[5] = (f16)b.y; r[6] = (f16)b.z; r[7] = (f16)b.w;
    return r;
}

// ---------------- router: fp32 logits, top-2, renormalized gates ----------------
__global__ __launch_bounds__(256) void router_kernel(
    const float* __restrict__ x, const float* __restrict__ gw,
    int* __restrict__ tok_e, float* __restrict__ tok_w, int* __restrict__ cnt)
{
    int wave = threadIdx.x >> 6;
    int lane = threadIdx.x & 63;
    int t = blockIdx.x * 4 + wave;
    if (t >= T_TOK) return;

    const float* xrow = x + (size_t)t * HDIM;
    float xv[16];
#pragma unroll
    for (int j = 0; j < 16; ++j) xv[j] = xrow[lane + 64 * j];

    float logits[NEXP];
#pragma unroll
    for (int e = 0; e < NEXP; ++e) {
        const float* gr = gw + (size_t)e * HDIM;
        float s = 0.f;
#pragma unroll
        for (int j = 0; j < 16; ++j) s += xv[j] * gr[lane + 64 * j];
#pragma unroll
        for (int o = 32; o > 0; o >>= 1) s += __shfl_xor(s, o, 64);
        logits[e] = s;
    }

    int i1 = 0; float m1 = logits[0];
#pragma unroll
    for (int e = 1; e < NEXP; ++e) if (logits[e] > m1) { m1 = logits[e]; i1 = e; }
    int i2 = -1; float m2 = -3.0e38f;
#pragma unroll
    for (int e = 0; e < NEXP; ++e) if (e != i1 && logits[e] > m2) { m2 = logits[e]; i2 = e; }

    float w1 = 1.f / (1.f + expf(m2 - m1));
    float w2 = 1.f - w1;

    if (lane == 0) {
        tok_e[t * 2 + 0] = i1; tok_e[t * 2 + 1] = i2;
        tok_w[t * 2 + 0] = w1; tok_w[t * 2 + 1] = w2;
        atomicAdd(&cnt[i1], 1);
        atomicAdd(&cnt[i2], 1);
    }
}

// ---------------- prefix: padded (to BM=128) expert bases ----------------
__global__ void prefix_kernel(const int* __restrict__ cnt, int* __restrict__ base,
                              int* __restrict__ total)
{
    if (threadIdx.x == 0) {
        int b = 0;
        for (int e = 0; e < NEXP; ++e) {
            base[e] = b;
            b += (cnt[e] + BM - 1) & ~(BM - 1);
        }
        base[NEXP] = b;
        *total = b;
    }
}

// ---------------- scatter: compact expert-major row list ----------------
__global__ __launch_bounds__(256) void scatter_kernel(
    const int* __restrict__ tok_e, const float* __restrict__ tok_w,
    const int* __restrict__ base, int* __restrict__ cnt2,
    int* __restrict__ rowslot, float* __restrict__ rowgate)
{
    int t = blockIdx.x * 256 + threadIdx.x;
    if (t >= T_TOK) return;
#pragma unroll
    for (int k = 0; k < 2; ++k) {
        int e = tok_e[t * 2 + k];
        int pos = atomicAdd(&cnt2[e], 1);
        int row = base[e] + pos;
        rowslot[row] = t * 2 + k;
        rowgate[row] = tok_w[t * 2 + k];
    }
}

// ---------------- GEMM1: 128x64 tile, BK=64, reg-prefetch pipeline, in-reg SwiGLU ----------------
// grid (48, 24); 4 waves, each 32 rows x 64 cols (gate n<2, up n>=2) -> 32 act cols/tile
__global__ __launch_bounds__(256, 3) void gemm1_kernel(
    const float* __restrict__ x, const float* __restrict__ w13,
    const int* __restrict__ rowslot, const int* __restrict__ base,
    const int* __restrict__ cnt, const int* __restrict__ total,
    f16* __restrict__ act)
{
    int row0 = blockIdx.x * BM;
    if (row0 >= *total) return;
    int nt = blockIdx.y;  // 0..23, 32 act cols each

    int e = 0;
#pragma unroll
    for (int i = 1; i < NEXP; ++i) if (base[i] <= row0) e = i;
    int basee = base[e], cnte = cnt[e];

    __shared__ f16 a_sm[128 * LDA];
    __shared__ f16 b_sm[64 * LDA];

    int tid = threadIdx.x;
    // A staging: 128 rows x 64 k; thread -> (row, 32 k-cols)
    int srowA = tid >> 1, scolA = (tid & 1) * 32;
    bool avalid = (unsigned)(row0 + srowA - basee) < (unsigned)cnte;
    const float* aptr = x;
    if (avalid) {
        int tok = rowslot[row0 + srowA] >> 1;
        aptr = x + (size_t)tok * HDIM + scolA;
    }
    // B staging: 64 h-cols x 64 k; thread -> (col, 16 k-cols)
    int srowB = tid >> 2, scolB = (tid & 3) * 16;
    int wrow = (srowB < 32) ? (nt * 32 + srowB) : (IDIM + nt * 32 + (srowB - 32));
    const float* bptr = w13 + (size_t)e * 2 * IDIM * HDIM + (size_t)wrow * HDIM + scolB;

    int wv = tid >> 6, lane = tid & 63, l16 = lane & 15, lk = lane >> 4;
    f32x4 acc[2][4] = {};
    float4 apre[8], bpre[4];

    auto load_pre = [&](int k0) {
        if (avalid) {
#pragma unroll
            for (int i = 0; i < 8; ++i) apre[i] = *(const float4*)(aptr + k0 + i * 4);
        } else {
#pragma unroll
            for (int i = 0; i < 8; ++i) apre[i] = float4{0.f, 0.f, 0.f, 0.f};
        }
#pragma unroll
        for (int i = 0; i < 4; ++i) bpre[i] = *(const float4*)(bptr + k0 + i * 4);
    };
    auto write_lds = [&]() {
#pragma unroll
        for (int i = 0; i < 4; ++i)
            *(f16x8*)&a_sm[srowA * LDA + scolA + i * 8] = cvt2(apre[2 * i], apre[2 * i + 1]);
#pragma unroll
        for (int i = 0; i < 2; ++i)
            *(f16x8*)&b_sm[srowB * LDA + scolB + i * 8] = cvt2(bpre[2 * i], bpre[2 * i + 1]);
    };

    load_pre(0);
    write_lds();
    __syncthreads();

    const int KT = HDIM / BK;  // 16
    for (int t = 0; t < KT; ++t) {
        if (t + 1 < KT) load_pre((t + 1) * BK);   // issue early: hides under MFMA
#pragma unroll
        for (int ks = 0; ks < 2; ++ks) {
            f16x8 af[2], bf[4];
#pragma unroll
            for (int m = 0; m < 2; ++m)
                af[m] = *(const f16x8*)&a_sm[(wv * 32 + m * 16 + l16) * LDA + ks * 32 + lk * 8];
#pragma unroll
            for (int n = 0; n < 4; ++n)
                bf[n] = *(const f16x8*)&b_sm[(n * 16 + l16) * LDA + ks * 32 + lk * 8];
#pragma unroll
            for (int m = 0; m < 2; ++m)
#pragma unroll
                for (int n = 0; n < 4; ++n)
                    acc[m][n] = __builtin_amdgcn_mfma_f32_16x16x32_f16(af[m], bf[n], acc[m][n], 0, 0, 0);
        }
        __syncthreads();
        if (t + 1 < KT) write_lds();
        __syncthreads();
    }

    // in-register SwiGLU: gate frag n pairs with up frag n+2 (same lane/reg)
#pragma unroll
    for (int m = 0; m < 2; ++m)
#pragma unroll
        for (int n = 0; n < 2; ++n)
#pragma unroll
            for (int j = 0; j < 4; ++j) {
                float hg = acc[m][n][j];
                float hu = acc[m][n + 2][j];
                float s = hg / (1.f + expf(-hg));
                int row = row0 + wv * 32 + m * 16 + lk * 4 + j;
                act[(size_t)row * IDIM + nt * 32 + n * 16 + l16] = (f16)(s * hu);
            }
}

// ---------------- GEMM2: 128x64 tile, BK=64, reg-prefetch, gate-scaled atomicAdd ----------------
// grid (48, 16); 4 waves, each 32 rows x 64 cols
__global__ __launch_bounds__(256, 3) void gemm2_kernel(
    const f16* __restrict__ act, const float* __restrict__ w2,
    const int* __restrict__ rowslot, const float* __restrict__ rowgate,
    const int* __restrict__ base, const int* __restrict__ cnt, const int* __restrict__ total,
    float* __restrict__ out)
{
    int row0 = blockIdx.x * BM;
    if (row0 >= *total) return;
    int nt = blockIdx.y;  // 0..15, 64 H-cols each

    int e = 0;
#pragma unroll
    for (int i = 1; i < NEXP; ++i) if (base[i] <= row0) e = i;
    int basee = base[e], cnte = cnt[e];

    __shared__ f16 a_sm[128 * LDA];
    __shared__ f16 b_sm[64 * LDA];

    int tid = threadIdx.x;
    int srowA = tid >> 1, scolA = (tid & 1) * 32;
    const f16* aptr = act + (size_t)(row0 + srowA) * IDIM + scolA;
    int srowB = tid >> 2, scolB = (tid & 3) * 16;
    const float* bptr = w2 + (size_t)e * HDIM * IDIM + (size_t)(nt * 64 + srowB) * IDIM + scolB;

    int wv = tid >> 6, lane = tid & 63, l16 = lane & 15, lk = lane >> 4;
    f32x4 acc[2][4] = {};
    f16x8 apre[4]; float4 bpre[4];

    auto load_pre = [&](int k0) {
#pragma unroll
        for (int i = 0; i < 4; ++i) apre[i] = *(const f16x8*)(aptr + k0 + i * 8);
#pragma unroll
        for (int i = 0; i < 4; ++i) bpre[i] = *(const float4*)(bptr + k0 + i * 4);
    };
    auto write_lds = [&]() {
#pragma unroll
        for (int i = 0; i < 4; ++i)
            *(f16x8*)&a_sm[srowA * LDA + scolA + i * 8] = apre[i];
#pragma unroll
        for (int i = 0; i < 2; ++i)
            *(f16x8*)&b_sm[srowB * LDA + scolB + i * 8] = cvt2(bpre[2 * i], bpre[2 * i + 1]);
    };

    load_pre(0);
    write_lds();
    __syncthreads();

    const int KT = IDIM / BK;  // 12
    for (int t = 0; t < KT; ++t) {
        if (t + 1 < KT) load_pre((t + 1) * BK);
#pragma unroll
        for (int ks = 0; ks < 2; ++ks) {
            f16x8 af[2], bf[4];
#pragma unroll
            for (int m = 0; m < 2; ++m)
                af[m] = *(const f16x8*)&a_sm[(wv * 32 + m * 16 + l16) * LDA + ks * 32 + lk * 8];
#pragma unroll
            for (int n = 0; n < 4; ++n)
                bf[n] = *(const f16x8*)&b_sm[(n * 16 + l16) * LDA + ks * 32 + lk * 8];
#pragma unroll
            for (int m = 0; m < 2; ++m)
#pragma unroll
                for (int n = 0; n < 4; ++n)
                    acc[m][n] = __builtin_amdgcn_mfma_f32_16x16x32_f16(af[m], bf[n], acc[m][n], 0, 0, 0);
        }
        __syncthreads();
        if (t + 1 < KT) write_lds();
        __syncthreads();
    }

#pragma unroll
    for (int m = 0; m < 2; ++m)
#pragma unroll
        for (int j = 0; j < 4; ++j) {
            int row = row0 + wv * 32 + m * 16 + lk * 4 + j;
            if ((unsigned)(row - basee) < (unsigned)cnte) {
                int s = rowslot[row];
                float g = rowgate[row];
                float* orow = out + (size_t)(s >> 1) * HDIM + nt * 64;
#pragma unroll
                for (int n = 0; n < 4; ++n)
                    atomicAdd(&orow[n * 16 + l16], g * acc[m][n][j]);
            }
        }
}

extern "C" void kernel_launch(void* const* d_in, const int* in_sizes, int n_in,
                              void* d_out, int out_size, void* d_ws, size_t ws_size,
                              hipStream_t stream) {
    const float* x   = (const float*)d_in[0];
    const float* gw  = (const float*)d_in[1];
    const float* w13 = (const float*)d_in[2];
    const float* w2  = (const float*)d_in[3];
    float* out = (float*)d_out;

    char* ws = (char*)d_ws;
    size_t off = 0;
    f16* act       = (f16*)(ws + off);   off += (size_t)MAXROWS * IDIM * 2;
    int* rowslot   = (int*)(ws + off);   off += (size_t)MAXROWS * 4;
    float* rowgate = (float*)(ws + off); off += (size_t)MAXROWS * 4;
    int* tok_e     = (int*)(ws + off);   off += (size_t)T_TOK * 2 * 4;
    float* tok_w   = (float*)(ws + off); off += (size_t)T_TOK * 2 * 4;
    int* cnt       = (int*)(ws + off);   off += 64;
    int* cnt2      = (int*)(ws + off);   off += 64;
    int* base      = (int*)(ws + off);   off += 128;
    int* total     = (int*)(ws + off);   off += 64;

    hipMemsetAsync(cnt, 0, 128, stream);  // cnt + cnt2 (contiguous)
    hipMemsetAsync(out, 0, (size_t)T_TOK * HDIM * 4, stream);

    router_kernel<<<T_TOK / 4, 256, 0, stream>>>(x, gw, tok_e, tok_w, cnt);
    prefix_kernel<<<1, 64, 0, stream>>>(cnt, base, total);
    scatter_kernel<<<T_TOK / 256, 256, 0, stream>>>(tok_e, tok_w, base, cnt2, rowslot, rowgate);

    dim3 g1(MAXROWS / BM, IDIM / 32);   // 48 x 24  (32 act cols per N-tile; was /128 = 12 -> half of act unwritten!)
    gemm1_kernel<<<g1, 256, 0, stream>>>(x, w13, rowslot, base, cnt, total, act);

    dim3 g2(MAXROWS / BM, HDIM / 64);   // 48 x 16
    gemm2_kernel<<<g2, 256, 0, stream>>>(act, w2, rowslot, rowgate, base, cnt, total, out);
}

// Round 7
// 349.775 us; speedup vs baseline: 1.1062x; 1.1062x over previous
//
#include <hip/hip_runtime.h>
#include <hip/hip_fp16.h>
#include <math.h>

#define T_TOK 2048
#define HDIM  1024
#define NEXP  16
#define IDIM  768
#define BM    128
#define BK    64
#define MAXROWS 6144   // >= 4096 + 16*127 = 6128

#define NW13  (NEXP * 2 * IDIM * HDIM)   // 25165824 floats
#define NW2   (NEXP * HDIM * IDIM)       // 12582912 floats
#define NWTOT (NW13 + NW2)

using f16   = _Float16;
using f16x8 = __attribute__((ext_vector_type(8))) _Float16;
using f32x4 = __attribute__((ext_vector_type(4))) float;

__device__ __forceinline__ f16x8 cvt2(float4 a, float4 b) {
    f16x8 r;
    r[0] = (f16)a.x; r[1] = (f16)a.y; r[2] = (f16)a.z; r[3] = (f16)a.w;
    r[4] = (f16)b.x; r[5] = (f16)b.y; r[6] = (f16)b.z; r[7] = (f16)b.w;
    return r;
}

// async global->LDS, 16 B per lane (global_load_lds_dwordx4). LDS dest must be
// linear in lane order: we pass base + tid*16 so firstlane(base)+lane*16 matches.
__device__ __forceinline__ void gload16(const f16* g, f16* l) {
    __builtin_amdgcn_global_load_lds(
        (const __attribute__((address_space(1))) unsigned int*)g,
        (__attribute__((address_space(3))) unsigned int*)l,
        16, 0, 0);
}

// ---------------- router: fp32 logits, top-2, renormalized gates ----------------
__global__ __launch_bounds__(256) void router_kernel(
    const float* __restrict__ x, const float* __restrict__ gw,
    int* __restrict__ tok_e, float* __restrict__ tok_w, int* __restrict__ cnt)
{
    int wave = threadIdx.x >> 6;
    int lane = threadIdx.x & 63;
    int t = blockIdx.x * 4 + wave;
    if (t >= T_TOK) return;

    const float* xrow = x + (size_t)t * HDIM;
    float xv[16];
#pragma unroll
    for (int j = 0; j < 16; ++j) xv[j] = xrow[lane + 64 * j];

    float logits[NEXP];
#pragma unroll
    for (int e = 0; e < NEXP; ++e) {
        const float* gr = gw + (size_t)e * HDIM;
        float s = 0.f;
#pragma unroll
        for (int j = 0; j < 16; ++j) s += xv[j] * gr[lane + 64 * j];
#pragma unroll
        for (int o = 32; o > 0; o >>= 1) s += __shfl_xor(s, o, 64);
        logits[e] = s;
    }

    int i1 = 0; float m1 = logits[0];
#pragma unroll
    for (int e = 1; e < NEXP; ++e) if (logits[e] > m1) { m1 = logits[e]; i1 = e; }
    int i2 = -1; float m2 = -3.0e38f;
#pragma unroll
    for (int e = 0; e < NEXP; ++e) if (e != i1 && logits[e] > m2) { m2 = logits[e]; i2 = e; }

    float w1 = 1.f / (1.f + expf(m2 - m1));
    float w2 = 1.f - w1;

    if (lane == 0) {
        tok_e[t * 2 + 0] = i1; tok_e[t * 2 + 1] = i2;
        tok_w[t * 2 + 0] = w1; tok_w[t * 2 + 1] = w2;
        atomicAdd(&cnt[i1], 1);
        atomicAdd(&cnt[i2], 1);
    }
}

// ---------------- prefix: padded (to BM=128) expert bases ----------------
__global__ void prefix_kernel(const int* __restrict__ cnt, int* __restrict__ base,
                              int* __restrict__ total)
{
    if (threadIdx.x == 0) {
        int b = 0;
        for (int e = 0; e < NEXP; ++e) {
            base[e] = b;
            b += (cnt[e] + BM - 1) & ~(BM - 1);
        }
        base[NEXP] = b;
        *total = b;
    }
}

// ---------------- scatter: compact expert-major row list ----------------
__global__ __launch_bounds__(256) void scatter_kernel(
    const int* __restrict__ tok_e, const float* __restrict__ tok_w,
    const int* __restrict__ base, int* __restrict__ cnt2,
    int* __restrict__ rowslot, float* __restrict__ rowgate)
{
    int t = blockIdx.x * 256 + threadIdx.x;
    if (t >= T_TOK) return;
#pragma unroll
    for (int k = 0; k < 2; ++k) {
        int e = tok_e[t * 2 + k];
        int pos = atomicAdd(&cnt2[e], 1);
        int row = base[e] + pos;
        rowslot[row] = t * 2 + k;
        rowgate[row] = tok_w[t * 2 + k];
    }
}

// ---------------- wcast: w13,w2 fp32 -> fp16, streaming ----------------
__global__ __launch_bounds__(256) void wcast_kernel(
    const float* __restrict__ w13, const float* __restrict__ w2,
    f16* __restrict__ w13h, f16* __restrict__ w2h)
{
    size_t stride = (size_t)gridDim.x * 256 * 8;
    for (size_t i8 = ((size_t)blockIdx.x * 256 + threadIdx.x) * 8; i8 < (size_t)NWTOT; i8 += stride) {
        const float* src; f16* dst; size_t off;
        if (i8 < (size_t)NW13) { src = w13; dst = w13h; off = i8; }
        else                   { src = w2;  dst = w2h;  off = i8 - NW13; }
        float4 a = *(const float4*)(src + off);
        float4 b = *(const float4*)(src + off + 4);
        *(f16x8*)(dst + off) = cvt2(a, b);
    }
}

// ---------------- xpack: gather token rows -> compact fp16 xg (pad rows zero) ----------------
__global__ __launch_bounds__(256) void xpack_kernel(
    const float* __restrict__ x, const int* __restrict__ rowslot,
    const int* __restrict__ base, const int* __restrict__ cnt,
    f16* __restrict__ xg)
{
    int gid = blockIdx.x * 256 + threadIdx.x;   // MAXROWS*128 threads
    int row = gid >> 7, c8 = (gid & 127) * 8;
    int e = 0;
#pragma unroll
    for (int i = 1; i < NEXP; ++i) if (base[i] <= row) e = i;
    f16x8 o = {};
    if ((unsigned)(row - base[e]) < (unsigned)cnt[e]) {
        int tok = rowslot[row] >> 1;
        const float* p = x + (size_t)tok * HDIM + c8;
        o = cvt2(*(const float4*)p, *(const float4*)(p + 4));
    }
    *(f16x8*)&xg[(size_t)row * HDIM + c8] = o;
}

// ---------------- GEMM1: 128x128 (64 gate + 64 up h-cols), m97-style, SwiGLU -> act ----------------
// static grid (12,48) remapped: nt'=0..11 (64 act cols), m'=0..47; 512 thr, 8 waves (4M x 2N)
__global__ __launch_bounds__(512, 4) void gemm1_kernel(
    const f16* __restrict__ xg, const f16* __restrict__ w13h,
    const int* __restrict__ base, const int* __restrict__ total,
    f16* __restrict__ act)
{
    // XCD-chunked swizzle: XCD x gets m' in {x, x+8, ..., x+40}, all nt per m (A-panel L2 reuse)
    int lin = blockIdx.x + blockIdx.y * 12;          // 0..575, XCD = lin % 8
    int swz = (lin % 8) * 72 + (lin / 8);            // chunk of 72 consecutive per XCD
    int chunk = swz / 12;                            // 0..47
    int mb = (chunk % 6) * 8 + (chunk / 6);          // m-tile, XCD-strided for balance
    int nt = swz % 12;

    int row0 = mb * BM;
    if (row0 >= *total) return;

    int e = 0;
#pragma unroll
    for (int i = 1; i < NEXP; ++i) if (base[i] <= row0) e = i;

    __shared__ f16 a_sm[128 * 64];
    __shared__ f16 b_sm[128 * 64];

    int tid = threadIdx.x;
    int r0 = tid >> 3;            // 0..63
    int cg = (tid & 7) * 8;       // k-col group (8 halfs = 16 B)

    const f16* ga0 = xg + (size_t)(row0 + r0) * HDIM + cg;
    const f16* ga1 = xg + (size_t)(row0 + 64 + r0) * HDIM + cg;
    const f16* wbase = w13h + (size_t)e * 2 * IDIM * HDIM;
    const f16* gb0 = wbase + (size_t)(nt * 64 + r0) * HDIM + cg;          // gate rows -> b_sm rows 0..63
    const f16* gb1 = wbase + (size_t)(IDIM + nt * 64 + r0) * HDIM + cg;   // up rows   -> b_sm rows 64..127

    int wv = tid >> 6, lane = tid & 63, l16 = lane & 15, lk = lane >> 4;
    int wr = wv >> 1;             // 0..3: 32-row strip
    int wc = wv & 1;              // 0..1: 32-col pair (gate+up)

    f32x4 acc[2][4] = {};

    for (int k0 = 0; k0 < HDIM; k0 += BK) {
        __syncthreads();
        gload16(ga0 + k0, &a_sm[tid * 8]);
        gload16(ga1 + k0, &a_sm[4096 + tid * 8]);
        gload16(gb0 + k0, &b_sm[tid * 8]);
        gload16(gb1 + k0, &b_sm[4096 + tid * 8]);
        __syncthreads();          // vmcnt(0) drain -> LDS tile ready
#pragma unroll
        for (int ks = 0; ks < 2; ++ks) {
            f16x8 af[2], bf[4];
#pragma unroll
            for (int m = 0; m < 2; ++m)
                af[m] = *(const f16x8*)&a_sm[(wr * 32 + m * 16 + l16) * 64 + ks * 32 + lk * 8];
#pragma unroll
            for (int n = 0; n < 2; ++n) {
                bf[n]     = *(const f16x8*)&b_sm[(wc * 32 + n * 16 + l16) * 64 + ks * 32 + lk * 8];
                bf[n + 2] = *(const f16x8*)&b_sm[(64 + wc * 32 + n * 16 + l16) * 64 + ks * 32 + lk * 8];
            }
#pragma unroll
            for (int m = 0; m < 2; ++m)
#pragma unroll
                for (int n = 0; n < 4; ++n)
                    acc[m][n] = __builtin_amdgcn_mfma_f32_16x16x32_f16(af[m], bf[n], acc[m][n], 0, 0, 0);
        }
    }

    // in-register SwiGLU: gate frag n pairs with up frag n+2 (same lane/reg)
#pragma unroll
    for (int m = 0; m < 2; ++m)
#pragma unroll
        for (int n = 0; n < 2; ++n)
#pragma unroll
            for (int j = 0; j < 4; ++j) {
                float hg = acc[m][n][j];
                float hu = acc[m][n + 2][j];
                float sg = hg / (1.f + expf(-hg));
                int row = row0 + wr * 32 + m * 16 + lk * 4 + j;
                act[(size_t)row * IDIM + nt * 64 + wc * 32 + n * 16 + l16] = (f16)(sg * hu);
            }
}

// ---------------- GEMM2: 128x64, m97-style, gate-scaled atomicAdd into out ----------------
// static grid (16,48) remapped: nt'=0..15 (64 H-cols), m'=0..47; 512 thr, 8 waves (4M x 2N)
__global__ __launch_bounds__(512, 4) void gemm2_kernel(
    const f16* __restrict__ act, const f16* __restrict__ w2h,
    const int* __restrict__ rowslot, const float* __restrict__ rowgate,
    const int* __restrict__ base, const int* __restrict__ cnt, const int* __restrict__ total,
    float* __restrict__ out)
{
    int lin = blockIdx.x + blockIdx.y * 16;          // 0..767, XCD = lin % 8
    int swz = (lin % 8) * 96 + (lin / 8);
    int chunk = swz / 16;                            // 0..47
    int mb = (chunk % 6) * 8 + (chunk / 6);
    int nt = swz % 16;

    int row0 = mb * BM;
    if (row0 >= *total) return;

    int e = 0;
#pragma unroll
    for (int i = 1; i < NEXP; ++i) if (base[i] <= row0) e = i;
    int basee = base[e], cnte = cnt[e];

    __shared__ f16 a_sm[128 * 64];
    __shared__ f16 b_sm[64 * 64];

    int tid = threadIdx.x;
    int r0 = tid >> 3, cg = (tid & 7) * 8;

    const f16* ga0 = act + (size_t)(row0 + r0) * IDIM + cg;
    const f16* ga1 = act + (size_t)(row0 + 64 + r0) * IDIM + cg;
    const f16* gb0 = w2h + (size_t)e * HDIM * IDIM + (size_t)(nt * 64 + r0) * IDIM + cg;

    int wv = tid >> 6, lane = tid & 63, l16 = lane & 15, lk = lane >> 4;
    int wr = wv >> 1, wc = wv & 1;

    f32x4 acc[2][2] = {};

    for (int k0 = 0; k0 < IDIM; k0 += BK) {   // 12 steps
        __syncthreads();
        gload16(ga0 + k0, &a_sm[tid * 8]);
        gload16(ga1 + k0, &a_sm[4096 + tid * 8]);
        gload16(gb0 + k0, &b_sm[tid * 8]);
        __syncthreads();
#pragma unroll
        for (int ks = 0; ks < 2; ++ks) {
            f16x8 af[2], bf[2];
#pragma unroll
            for (int m = 0; m < 2; ++m)
                af[m] = *(const f16x8*)&a_sm[(wr * 32 + m * 16 + l16) * 64 + ks * 32 + lk * 8];
#pragma unroll
            for (int n = 0; n < 2; ++n)
                bf[n] = *(const f16x8*)&b_sm[(wc * 32 + n * 16 + l16) * 64 + ks * 32 + lk * 8];
#pragma unroll
            for (int m = 0; m < 2; ++m)
#pragma unroll
                for (int n = 0; n < 2; ++n)
                    acc[m][n] = __builtin_amdgcn_mfma_f32_16x16x32_f16(af[m], bf[n], acc[m][n], 0, 0, 0);
        }
    }

#pragma unroll
    for (int m = 0; m < 2; ++m)
#pragma unroll
        for (int j = 0; j < 4; ++j) {
            int row = row0 + wr * 32 + m * 16 + lk * 4 + j;
            if ((unsigned)(row - basee) < (unsigned)cnte) {
                int sl = rowslot[row];
                float g = rowgate[row];
                float* orow = out + (size_t)(sl >> 1) * HDIM + nt * 64 + wc * 32;
#pragma unroll
                for (int n = 0; n < 2; ++n)
                    atomicAdd(&orow[n * 16 + l16], g * acc[m][n][j]);
            }
        }
}

extern "C" void kernel_launch(void* const* d_in, const int* in_sizes, int n_in,
                              void* d_out, int out_size, void* d_ws, size_t ws_size,
                              hipStream_t stream) {
    const float* x   = (const float*)d_in[0];
    const float* gw  = (const float*)d_in[1];
    const float* w13 = (const float*)d_in[2];
    const float* w2  = (const float*)d_in[3];
    float* out = (float*)d_out;

    char* ws = (char*)d_ws;
    size_t off = 0;
    f16* w13h      = (f16*)(ws + off);   off += (size_t)NW13 * 2;            // 50.3 MB
    f16* w2h       = (f16*)(ws + off);   off += (size_t)NW2 * 2;             // 25.2 MB
    f16* xg        = (f16*)(ws + off);   off += (size_t)MAXROWS * HDIM * 2;  // 12.6 MB
    f16* act       = (f16*)(ws + off);   off += (size_t)MAXROWS * IDIM * 2;  //  9.4 MB
    int* rowslot   = (int*)(ws + off);   off += (size_t)MAXROWS * 4;
    float* rowgate = (float*)(ws + off); off += (size_t)MAXROWS * 4;
    int* tok_e     = (int*)(ws + off);   off += (size_t)T_TOK * 2 * 4;
    float* tok_w   = (float*)(ws + off); off += (size_t)T_TOK * 2 * 4;
    int* cnt       = (int*)(ws + off);   off += 64;
    int* cnt2      = (int*)(ws + off);   off += 64;
    int* base      = (int*)(ws + off);   off += 128;
    int* total     = (int*)(ws + off);   off += 64;

    hipMemsetAsync(cnt, 0, 128, stream);  // cnt + cnt2 (contiguous)
    hipMemsetAsync(out, 0, (size_t)T_TOK * HDIM * 4, stream);

    router_kernel<<<T_TOK / 4, 256, 0, stream>>>(x, gw, tok_e, tok_w, cnt);
    prefix_kernel<<<1, 64, 0, stream>>>(cnt, base, total);
    scatter_kernel<<<T_TOK / 256, 256, 0, stream>>>(tok_e, tok_w, base, cnt2, rowslot, rowgate);

    wcast_kernel<<<2048, 256, 0, stream>>>(w13, w2, w13h, w2h);
    xpack_kernel<<<(MAXROWS * 128) / 256, 256, 0, stream>>>(x, rowslot, base, cnt, xg);

    dim3 g1(12, 48);   // 12 nt x 48 m (remapped in-kernel)
    gemm1_kernel<<<g1, 512, 0, stream>>>(xg, w13h, base, total, act);

    dim3 g2(16, 48);   // 16 nt x 48 m
    gemm2_kernel<<<g2, 512, 0, stream>>>(act, w2h, rowslot, rowgate, base, cnt, total, out);
}

// Round 8
// 342.798 us; speedup vs baseline: 1.1287x; 1.0204x over previous
//
#include <hip/hip_runtime.h>
#include <hip/hip_fp16.h>
#include <math.h>

#define T_TOK 2048
#define HDIM  1024
#define NEXP  16
#define IDIM  768
#define BM    128
#define BK    64
#define MAXROWS 6144   // >= 4096 + 16*127 = 6128

#define NW13  (NEXP * 2 * IDIM * HDIM)   // 25165824 floats = 2048*256*16*3 exactly
#define NW2   (NEXP * HDIM * IDIM)       // 12582912 floats = 1024*256*16*3 exactly
#define WB1   2048
#define WB2   1024

using f16   = _Float16;
using f16x8 = __attribute__((ext_vector_type(8))) _Float16;
using f32x4 = __attribute__((ext_vector_type(4))) float;

__device__ __forceinline__ f16x8 cvt2(float4 a, float4 b) {
    f16x8 r;
    r[0] = (f16)a.x; r[1] = (f16)a.y; r[2] = (f16)a.z; r[3] = (f16)a.w;
    r[4] = (f16)b.x; r[5] = (f16)b.y; r[6] = (f16)b.z; r[7] = (f16)b.w;
    return r;
}

// async global->LDS, 16 B per lane (global_load_lds_dwordx4), linear lane order
__device__ __forceinline__ void gload16(const f16* g, f16* l) {
    __builtin_amdgcn_global_load_lds(
        (const __attribute__((address_space(1))) unsigned int*)g,
        (__attribute__((address_space(3))) unsigned int*)l,
        16, 0, 0);
}

// ---------------- router: fp32 logits, top-2, renormalized gates ----------------
__global__ __launch_bounds__(256) void router_kernel(
    const float* __restrict__ x, const float* __restrict__ gw,
    int* __restrict__ tok_e, float* __restrict__ tok_w, int* __restrict__ cnt)
{
    int wave = threadIdx.x >> 6;
    int lane = threadIdx.x & 63;
    int t = blockIdx.x * 4 + wave;
    if (t >= T_TOK) return;

    const float* xrow = x + (size_t)t * HDIM;
    float xv[16];
#pragma unroll
    for (int j = 0; j < 16; ++j) xv[j] = xrow[lane + 64 * j];

    float logits[NEXP];
#pragma unroll
    for (int e = 0; e < NEXP; ++e) {
        const float* gr = gw + (size_t)e * HDIM;
        float s = 0.f;
#pragma unroll
        for (int j = 0; j < 16; ++j) s += xv[j] * gr[lane + 64 * j];
#pragma unroll
        for (int o = 32; o > 0; o >>= 1) s += __shfl_xor(s, o, 64);
        logits[e] = s;
    }

    int i1 = 0; float m1 = logits[0];
#pragma unroll
    for (int e = 1; e < NEXP; ++e) if (logits[e] > m1) { m1 = logits[e]; i1 = e; }
    int i2 = -1; float m2 = -3.0e38f;
#pragma unroll
    for (int e = 0; e < NEXP; ++e) if (e != i1 && logits[e] > m2) { m2 = logits[e]; i2 = e; }

    float w1 = 1.f / (1.f + expf(m2 - m1));
    float w2 = 1.f - w1;

    if (lane == 0) {
        tok_e[t * 2 + 0] = i1; tok_e[t * 2 + 1] = i2;
        tok_w[t * 2 + 0] = w1; tok_w[t * 2 + 1] = w2;
        atomicAdd(&cnt[i1], 1);
        atomicAdd(&cnt[i2], 1);
    }
}

// ---------------- prefix: padded (to BM=128) expert bases ----------------
__global__ void prefix_kernel(const int* __restrict__ cnt, int* __restrict__ base,
                              int* __restrict__ total)
{
    if (threadIdx.x == 0) {
        int b = 0;
        for (int e = 0; e < NEXP; ++e) {
            base[e] = b;
            b += (cnt[e] + BM - 1) & ~(BM - 1);
        }
        base[NEXP] = b;
        *total = b;
    }
}

// ---------------- scatter: compact expert-major row list + token->row map ----------------
__global__ __launch_bounds__(256) void scatter_kernel(
    const int* __restrict__ tok_e, const float* __restrict__ tok_w,
    const int* __restrict__ base, int* __restrict__ cnt2,
    int* __restrict__ rowslot, int* __restrict__ tok2row)
{
    int t = blockIdx.x * 256 + threadIdx.x;
    if (t >= T_TOK) return;
#pragma unroll
    for (int k = 0; k < 2; ++k) {
        int e = tok_e[t * 2 + k];
        int pos = atomicAdd(&cnt2[e], 1);
        int row = base[e] + pos;
        rowslot[row] = t * 2 + k;
        tok2row[t * 2 + k] = row;
    }
}

// ---------------- wcast: fp32 -> fp16, branch-free block-range split ----------------
// blocks [0,WB1) -> w13 (exactly 3 iters/thread), [WB1,WB1+WB2) -> w2 (exactly 3)
__global__ __launch_bounds__(256) void wcast_kernel(
    const float* __restrict__ w13, const float* __restrict__ w2,
    f16* __restrict__ w13h, f16* __restrict__ w2h)
{
    const float* src; f16* dst; size_t stride; int inblk;
    if (blockIdx.x < WB1) { src = w13; dst = w13h; inblk = blockIdx.x;       stride = (size_t)WB1 * 256 * 16; }
    else                  { src = w2;  dst = w2h;  inblk = blockIdx.x - WB1; stride = (size_t)WB2 * 256 * 16; }
    size_t p = ((size_t)inblk * 256 + threadIdx.x) * 16;
#pragma unroll
    for (int it = 0; it < 3; ++it, p += stride) {
        float4 a0 = *(const float4*)(src + p);
        float4 a1 = *(const float4*)(src + p + 4);
        float4 a2 = *(const float4*)(src + p + 8);
        float4 a3 = *(const float4*)(src + p + 12);
        *(f16x8*)(dst + p)     = cvt2(a0, a1);
        *(f16x8*)(dst + p + 8) = cvt2(a2, a3);
    }
}

// ---------------- xpack: gather token rows -> compact fp16 xg (pad rows zero) ----------------
__global__ __launch_bounds__(256) void xpack_kernel(
    const float* __restrict__ x, const int* __restrict__ rowslot,
    const int* __restrict__ base, const int* __restrict__ cnt,
    f16* __restrict__ xg)
{
    int gid = blockIdx.x * 256 + threadIdx.x;   // MAXROWS*128 threads
    int row = gid >> 7, c8 = (gid & 127) * 8;
    int e = 0;
#pragma unroll
    for (int i = 1; i < NEXP; ++i) if (base[i] <= row) e = i;
    f16x8 o = {};
    if ((unsigned)(row - base[e]) < (unsigned)cnt[e]) {
        int tok = rowslot[row] >> 1;
        const float* p = x + (size_t)tok * HDIM + c8;
        o = cvt2(*(const float4*)p, *(const float4*)(p + 4));
    }
    *(f16x8*)&xg[(size_t)row * HDIM + c8] = o;
}

// ---------------- GEMM1: 128x128 (64 gate + 64 up h-cols), m97-style, SwiGLU -> act ----------------
// static grid (12,48) remapped; 512 thr, 8 waves (4M x 2N)
__global__ __launch_bounds__(512, 4) void gemm1_kernel(
    const f16* __restrict__ xg, const f16* __restrict__ w13h,
    const int* __restrict__ base, const int* __restrict__ total,
    f16* __restrict__ act)
{
    int lin = blockIdx.x + blockIdx.y * 12;          // 0..575, XCD = lin % 8
    int swz = (lin % 8) * 72 + (lin / 8);
    int chunk = swz / 12;                            // 0..47
    int mb = (chunk % 6) * 8 + (chunk / 6);
    int nt = swz % 12;

    int row0 = mb * BM;
    if (row0 >= *total) return;

    int e = 0;
#pragma unroll
    for (int i = 1; i < NEXP; ++i) if (base[i] <= row0) e = i;

    __shared__ f16 a_sm[128 * 64];
    __shared__ f16 b_sm[128 * 64];

    int tid = threadIdx.x;
    int r0 = tid >> 3;
    int cg = (tid & 7) * 8;

    const f16* ga0 = xg + (size_t)(row0 + r0) * HDIM + cg;
    const f16* ga1 = xg + (size_t)(row0 + 64 + r0) * HDIM + cg;
    const f16* wbase = w13h + (size_t)e * 2 * IDIM * HDIM;
    const f16* gb0 = wbase + (size_t)(nt * 64 + r0) * HDIM + cg;
    const f16* gb1 = wbase + (size_t)(IDIM + nt * 64 + r0) * HDIM + cg;

    int wv = tid >> 6, lane = tid & 63, l16 = lane & 15, lk = lane >> 4;
    int wr = wv >> 1;
    int wc = wv & 1;

    f32x4 acc[2][4] = {};

    for (int k0 = 0; k0 < HDIM; k0 += BK) {
        __syncthreads();
        gload16(ga0 + k0, &a_sm[tid * 8]);
        gload16(ga1 + k0, &a_sm[4096 + tid * 8]);
        gload16(gb0 + k0, &b_sm[tid * 8]);
        gload16(gb1 + k0, &b_sm[4096 + tid * 8]);
        __syncthreads();
#pragma unroll
        for (int ks = 0; ks < 2; ++ks) {
            f16x8 af[2], bf[4];
#pragma unroll
            for (int m = 0; m < 2; ++m)
                af[m] = *(const f16x8*)&a_sm[(wr * 32 + m * 16 + l16) * 64 + ks * 32 + lk * 8];
#pragma unroll
            for (int n = 0; n < 2; ++n) {
                bf[n]     = *(const f16x8*)&b_sm[(wc * 32 + n * 16 + l16) * 64 + ks * 32 + lk * 8];
                bf[n + 2] = *(const f16x8*)&b_sm[(64 + wc * 32 + n * 16 + l16) * 64 + ks * 32 + lk * 8];
            }
#pragma unroll
            for (int m = 0; m < 2; ++m)
#pragma unroll
                for (int n = 0; n < 4; ++n)
                    acc[m][n] = __builtin_amdgcn_mfma_f32_16x16x32_f16(af[m], bf[n], acc[m][n], 0, 0, 0);
        }
    }

    // in-register SwiGLU: gate frag n pairs with up frag n+2 (same lane/reg)
#pragma unroll
    for (int m = 0; m < 2; ++m)
#pragma unroll
        for (int n = 0; n < 2; ++n)
#pragma unroll
            for (int j = 0; j < 4; ++j) {
                float hg = acc[m][n][j];
                float hu = acc[m][n + 2][j];
                float sg = hg / (1.f + expf(-hg));
                int row = row0 + wr * 32 + m * 16 + lk * 4 + j;
                act[(size_t)row * IDIM + nt * 64 + wc * 32 + n * 16 + l16] = (f16)(sg * hu);
            }
}

// ---------------- GEMM2: 128x64, m97-style, plain fp16 slot-writes into z ----------------
// static grid (16,48) remapped; 512 thr, 8 waves (4M x 2N)
__global__ __launch_bounds__(512, 4) void gemm2_kernel(
    const f16* __restrict__ act, const f16* __restrict__ w2h,
    const int* __restrict__ base, const int* __restrict__ total,
    f16* __restrict__ z)
{
    int lin = blockIdx.x + blockIdx.y * 16;          // 0..767
    int swz = (lin % 8) * 96 + (lin / 8);
    int chunk = swz / 16;                            // 0..47
    int mb = (chunk % 6) * 8 + (chunk / 6);
    int nt = swz % 16;

    int row0 = mb * BM;
    if (row0 >= *total) return;

    int e = 0;
#pragma unroll
    for (int i = 1; i < NEXP; ++i) if (base[i] <= row0) e = i;

    __shared__ f16 a_sm[128 * 64];
    __shared__ f16 b_sm[64 * 64];

    int tid = threadIdx.x;
    int r0 = tid >> 3, cg = (tid & 7) * 8;

    const f16* ga0 = act + (size_t)(row0 + r0) * IDIM + cg;
    const f16* ga1 = act + (size_t)(row0 + 64 + r0) * IDIM + cg;
    const f16* gb0 = w2h + (size_t)e * HDIM * IDIM + (size_t)(nt * 64 + r0) * IDIM + cg;

    int wv = tid >> 6, lane = tid & 63, l16 = lane & 15, lk = lane >> 4;
    int wr = wv >> 1, wc = wv & 1;

    f32x4 acc[2][2] = {};

    for (int k0 = 0; k0 < IDIM; k0 += BK) {   // 12 steps
        __syncthreads();
        gload16(ga0 + k0, &a_sm[tid * 8]);
        gload16(ga1 + k0, &a_sm[4096 + tid * 8]);
        gload16(gb0 + k0, &b_sm[tid * 8]);
        __syncthreads();
#pragma unroll
        for (int ks = 0; ks < 2; ++ks) {
            f16x8 af[2], bf[2];
#pragma unroll
            for (int m = 0; m < 2; ++m)
                af[m] = *(const f16x8*)&a_sm[(wr * 32 + m * 16 + l16) * 64 + ks * 32 + lk * 8];
#pragma unroll
            for (int n = 0; n < 2; ++n)
                bf[n] = *(const f16x8*)&b_sm[(wc * 32 + n * 16 + l16) * 64 + ks * 32 + lk * 8];
#pragma unroll
            for (int m = 0; m < 2; ++m)
#pragma unroll
                for (int n = 0; n < 2; ++n)
                    acc[m][n] = __builtin_amdgcn_mfma_f32_16x16x32_f16(af[m], bf[n], acc[m][n], 0, 0, 0);
        }
    }

#pragma unroll
    for (int m = 0; m < 2; ++m)
#pragma unroll
        for (int j = 0; j < 4; ++j) {
            int row = row0 + wr * 32 + m * 16 + lk * 4 + j;
#pragma unroll
            for (int n = 0; n < 2; ++n)
                z[(size_t)row * HDIM + nt * 64 + wc * 32 + n * 16 + l16] = (f16)acc[m][n][j];
        }
}

// ---------------- combine: out[t] = g0*z[row0] + g1*z[row1] (overwrites all of out) ----------------
__global__ __launch_bounds__(256) void combine_kernel(
    const f16* __restrict__ z, const int* __restrict__ tok2row,
    const float* __restrict__ tok_w, float* __restrict__ out)
{
    int gid = blockIdx.x * 256 + threadIdx.x;   // T_TOK*128 threads
    int t = gid >> 7, c8 = (gid & 127) * 8;
    int r0 = tok2row[2 * t], r1 = tok2row[2 * t + 1];
    float g0 = tok_w[2 * t], g1 = tok_w[2 * t + 1];
    f16x8 z0 = *(const f16x8*)&z[(size_t)r0 * HDIM + c8];
    f16x8 z1 = *(const f16x8*)&z[(size_t)r1 * HDIM + c8];
    float* o = out + (size_t)t * HDIM + c8;
#pragma unroll
    for (int i = 0; i < 8; ++i)
        o[i] = g0 * (float)z0[i] + g1 * (float)z1[i];
}

extern "C" void kernel_launch(void* const* d_in, const int* in_sizes, int n_in,
                              void* d_out, int out_size, void* d_ws, size_t ws_size,
                              hipStream_t stream) {
    const float* x   = (const float*)d_in[0];
    const float* gw  = (const float*)d_in[1];
    const float* w13 = (const float*)d_in[2];
    const float* w2  = (const float*)d_in[3];
    float* out = (float*)d_out;

    char* ws = (char*)d_ws;
    size_t off = 0;
    f16* w13h      = (f16*)(ws + off);   off += (size_t)NW13 * 2;            // 50.3 MB
    f16* w2h       = (f16*)(ws + off);   off += (size_t)NW2 * 2;             // 25.2 MB
    f16* xg        = (f16*)(ws + off);   off += (size_t)MAXROWS * HDIM * 2;  // 12.6 MB (reused as z)
    f16* act       = (f16*)(ws + off);   off += (size_t)MAXROWS * IDIM * 2;  //  9.4 MB
    int* rowslot   = (int*)(ws + off);   off += (size_t)MAXROWS * 4;
    int* tok2row   = (int*)(ws + off);   off += (size_t)T_TOK * 2 * 4;
    int* tok_e     = (int*)(ws + off);   off += (size_t)T_TOK * 2 * 4;
    float* tok_w   = (float*)(ws + off); off += (size_t)T_TOK * 2 * 4;
    int* cnt       = (int*)(ws + off);   off += 64;
    int* cnt2      = (int*)(ws + off);   off += 64;
    int* base      = (int*)(ws + off);   off += 128;
    int* total     = (int*)(ws + off);   off += 64;
    f16* zbuf      = xg;   // xg is dead after gemm1; z overlays it

    hipMemsetAsync(cnt, 0, 128, stream);  // cnt + cnt2 (contiguous)

    router_kernel<<<T_TOK / 4, 256, 0, stream>>>(x, gw, tok_e, tok_w, cnt);
    prefix_kernel<<<1, 64, 0, stream>>>(cnt, base, total);
    scatter_kernel<<<T_TOK / 256, 256, 0, stream>>>(tok_e, tok_w, base, cnt2, rowslot, tok2row);

    wcast_kernel<<<WB1 + WB2, 256, 0, stream>>>(w13, w2, w13h, w2h);
    xpack_kernel<<<(MAXROWS * 128) / 256, 256, 0, stream>>>(x, rowslot, base, cnt, xg);

    dim3 g1(12, 48);
    gemm1_kernel<<<g1, 512, 0, stream>>>(xg, w13h, base, total, act);

    dim3 g2(16, 48);
    gemm2_kernel<<<g2, 512, 0, stream>>>(act, w2h, base, total, zbuf);

    combine_kernel<<<(T_TOK * 128) / 256, 256, 0, stream>>>(zbuf, tok2row, tok_w, out);
}